// Round 10
// baseline (576.277 us; speedup 1.0000x reference)
//
#include <hip/hip_runtime.h>
#include <math.h>

typedef short bf16x8 __attribute__((ext_vector_type(8)));
typedef float f32x4 __attribute__((ext_vector_type(4)));

#define HH 8
#define NN 4096
#define DIP 256   // ip(240) + s(16), no pad
#define DDX 256   // qdx: [hi|hi | mid|lo | mid32-47+16z | hi32-47+16z]
#define DKM 192   // kmx: [mid | lo | hi | hi]
#define DV 272
#define BN 32
#define NT (NN/BN)

typedef const __attribute__((address_space(1))) unsigned int* gp_t;
typedef __attribute__((address_space(3))) unsigned int* lp_t;
__device__ __forceinline__ void gload16(const void* g, void* l) {
    __builtin_amdgcn_global_load_lds((gp_t)g, (lp_t)l, 16, 0, 0);
}

__device__ __forceinline__ unsigned short f2bf(float f) {
    unsigned int u = __float_as_uint(f);
    u = (u + 0x7fffu + ((u >> 16) & 1u)) >> 16;   // RNE
    return (unsigned short)u;
}
__device__ __forceinline__ float bf2f(unsigned short h) {
    return __uint_as_float(((unsigned int)h) << 16);
}
__device__ __forceinline__ float fexp2(float x) {   // 2^x, single v_exp_f32
    float r;
    asm("v_exp_f32 %0, %1" : "=v"(r) : "v"(x));
    return r;
}

#define MFMA16(A,B,C) __builtin_amdgcn_mfma_f32_16x16x32_bf16((A),(B),(C),0,0,0)

// ---- stage 1a: features. fip[256] = ip+s. fdx: Q-mode 256 cols / K-mode 192 cols ----
__global__ void feat_kernel(const float* __restrict__ mv,
                            const float* __restrict__ sv,
                            const float* __restrict__ basis,
                            float scale, int qmode,
                            unsigned short* __restrict__ fip,
                            unsigned short* __restrict__ fdx)
{
    __shared__ float sb[150];
    int t = threadIdx.x;
    if (t < 150) sb[t] = basis[t];
    __syncthreads();
    int row = blockIdx.x * 32 + (t >> 3);   // (h*4096+n)
    int c = t & 7;
    const float* m = mv + (size_t)row * 256 + c * 32;
    float f[32];
    #pragma unroll
    for (int i = 0; i < 8; ++i) {
        float4 v = ((const float4*)m)[i];
        f[i*4+0] = v.x; f[i*4+1] = v.y; f[i*4+2] = v.z; f[i*4+3] = v.w;
    }
    unsigned short* ip = fip + (size_t)row * DIP;
    unsigned short* dx = fdx + (size_t)row * (qmode ? DDX : DKM);
    #pragma unroll
    for (int j = 0; j < 30; ++j)
        ip[c*30 + j] = f2bf(f[1+j] * scale);
    if (c < 2) {
        #pragma unroll
        for (int i = 0; i < 8; ++i)
            ip[240 + c*8 + i] = f2bf(sv[(size_t)row*16 + c*8 + i] * scale);
    }
    float nn = 1.0f / sqrtf(f[5]*f[5] + 0.001f);
    float tn[5];
    #pragma unroll
    for (int x = 0; x < 5; ++x) tn[x] = f[1+x] * nn;
    #pragma unroll
    for (int z = 0; z < 6; ++z) {
        float acc = 0.f;
        #pragma unroll
        for (int x = 0; x < 5; ++x) {
            #pragma unroll
            for (int y = 0; y < 5; ++y)
                acc = fmaf(sb[(x*5+y)*6 + z] * tn[x], tn[y], acc);
        }
        acc *= scale;
        unsigned short hi = f2bf(acc);
        float r1 = acc - bf2f(hi);
        unsigned short mi = f2bf(r1);
        float r2 = r1 - bf2f(mi);
        unsigned short lo = f2bf(r2);
        int cz = c*6 + z;
        if (qmode) {
            dx[cz]      = hi;  dx[48 + cz]  = hi;
            dx[96 + cz] = mi;  dx[144 + cz] = lo;
            if (cz < 16) { dx[208 + cz] = 0; dx[240 + cz] = 0; }
            if (cz >= 32) { dx[160 + cz] = mi; dx[192 + cz] = hi; }
        } else {
            dx[cz]      = mi;  dx[48 + cz]  = lo;
            dx[96 + cz] = hi;  dx[144 + cz] = hi;
        }
    }
}

// ---- stage 1b: V -> transposed bf16 [8][272][4096] ----
__global__ void vtrans_kernel(const float* __restrict__ vmv,
                              const float* __restrict__ vs,
                              unsigned short* __restrict__ dst)
{
    __shared__ unsigned short tile[64][DV];
    int blk = blockIdx.x;
    int h = blk >> 6;
    int n0 = (blk & 63) << 6;
    int t = threadIdx.x;
    #pragma unroll
    for (int it = 0; it < 16; ++it) {
        int v = t + it*256;
        int r = v >> 6;
        int sg = v & 63;
        float4 x = *(const float4*)(vmv + ((size_t)(h*NN + n0 + r))*256 + sg*4);
        tile[r][sg*4+0] = f2bf(x.x);
        tile[r][sg*4+1] = f2bf(x.y);
        tile[r][sg*4+2] = f2bf(x.z);
        tile[r][sg*4+3] = f2bf(x.w);
    }
    #pragma unroll
    for (int it = 0; it < 4; ++it) {
        int v = t + it*256;
        int r = v >> 4;
        int si = v & 15;
        tile[r][256 + si] = f2bf(vs[((size_t)(h*NN + n0 + r))*16 + si]);
    }
    __syncthreads();
    #pragma unroll
    for (int it = 0; it < 17; ++it) {
        int v = t + it*256;
        int dd = v >> 4;
        int sg = v & 15;
        ushort4 o;
        o.x = tile[sg*4+0][dd];
        o.y = tile[sg*4+1][dd];
        o.z = tile[sg*4+2][dd];
        o.w = tile[sg*4+3][dd];
        *(ushort4*)(dst + ((size_t)(h*DV + dd))*NN + n0 + sg*4) = o;
    }
}

// ---- stage 2: flash attention, 4 fat waves x 32 q-rows, 1 wave/SIMD, A-frag reuse ----
__global__ __launch_bounds__(256, 1)
void attn_kernel(const unsigned short* __restrict__ Qip,
                 const unsigned short* __restrict__ Qdx,
                 const unsigned short* __restrict__ Kip,
                 const unsigned short* __restrict__ Kmx,
                 const unsigned short* __restrict__ Vt,
                 float* __restrict__ out)
{
    // LDS (ush): kt 2x8192 [0,16384) | kmx 2x6144 [16384,28672) | vt 2x8704 [28672,46080) | pb 4096 [46080,50176)
    __shared__ __align__(128) unsigned short smem[50176];   // 100,352 B

    int blk = blockIdx.x;
    int sbk = ((blk & 7) << 5) | (blk >> 3);   // grid 256, bijective XCD swizzle; XCD x = head x
    int h = sbk >> 5;
    int q0 = (sbk & 31) * 128;
    int tid = threadIdx.x;
    int w = tid >> 6;
    int lane = tid & 63;
    int l15 = lane & 15;
    int l4 = lane >> 4;
    int l7l = l15 & 3;
    int l7h = (l15 >> 2) & 1;

    // Q fragments, two 16-row halves per wave (B-operand: col=q=l15)
    const unsigned short* qipr = Qip + (size_t)(h*NN + q0 + w*32 + l15) * DIP + l4*8;
    const unsigned short* qdxr = Qdx + (size_t)(h*NN + q0 + w*32 + l15) * DDX + l4*8;
    bf16x8 qip0[8], qip1[8], qdx0[8], qdx1[8];
    #pragma unroll
    for (int ks = 0; ks < 8; ++ks) {
        qip0[ks] = *(const bf16x8*)(qipr + ks*32);
        qip1[ks] = *(const bf16x8*)(qipr + 16*DIP + ks*32);
        qdx0[ks] = *(const bf16x8*)(qdxr + ks*32);
        qdx1[ks] = *(const bf16x8*)(qdxr + 16*DDX + ks*32);
    }

    // LDS read bases (bytes)
    int cl16 = (l4 ^ l7l) * 16;
    int kbE = l15*512 + cl16 + l7h*64;
    int kbO = l15*512 + cl16 + 64 - l7h*64;
    int mA  = l15*384 + cl16 + l7h*64;
    int mB  = l15*384 + cl16 + 64 - l7h*64;
    int vlane = (l15>>1)*128 + (((((l15&1)<<2) | l4) ^ (l15>>1)) << 4);
    int pbA = 92160 + w*2048 + l15*64;
    int pA0 = pbA + ((((l4>>1)    ) ^ l7l) << 4) + (l4&1)*8;
    int pA1 = pbA + ((((l4>>1) + 2) ^ l7l) << 4) + (l4&1)*8;
    int pRA = pbA + ((l4 ^ l7l) << 4);
    int pB0 = pA0 + 1024, pB1 = pA1 + 1024, pRB = pRA + 1024;

    // DMA source offsets (ush), loop-invariant (256-thread slot maps)
    int kto0, kto1, kto2, kto3, kmo0, kmo1, kmo2, vto0, vto1, vto2, vto3, vto4;
#define KTFL(SLOT, DST) { int r_ = (SLOT) >> 5, fp_ = (SLOT) & 31; \
    int fl_ = (fp_ & 24) | ((((fp_>>2)&1) ^ ((r_>>2)&1)) << 2) | ((fp_&3) ^ (r_&3)); \
    DST = r_*DIP + fl_*8; }
#define KMFL(SLOT, DST) { int r_ = (SLOT)/24, fp_ = (SLOT)%24; \
    int g_ = fp_>>3, po_ = fp_&7; \
    int pl_ = ((((po_>>2)&1) ^ ((r_>>2)&1)) << 2) | ((po_&3) ^ (r_&3)); \
    DST = r_*DKM + (g_*8 + pl_)*8; }
#define VTF(SLOT, DST) { int ch_ = (SLOT) >> 3, ws_ = (SLOT) & 7; int lw_ = ws_ ^ (ch_&7); \
    DST = (ch_*2 + (lw_>>2))*NN + (lw_&3)*8; }
    KTFL(tid, kto0) KTFL(tid+256, kto1) KTFL(tid+512, kto2) KTFL(tid+768, kto3)
    KMFL(tid, kmo0) KMFL(tid+256, kmo1) KMFL(tid+512, kmo2)
    VTF(tid, vto0) VTF(tid+256, vto1) VTF(tid+512, vto2) VTF(tid+768, vto3) VTF(tid+1024, vto4)
#undef KTFL
#undef KMFL
#undef VTF

    const unsigned short* kiph = Kip + (size_t)h*NN*DIP;
    const unsigned short* kmxh = Kmx + (size_t)h*NN*DKM;
    const unsigned short* vh   = Vt  + (size_t)h*DV*NN;

    f32x4 zero = {0.f, 0.f, 0.f, 0.f};
    f32x4 oaccA[17], oaccB[17];
    #pragma unroll
    for (int ct = 0; ct < 17; ++ct) { oaccA[ct] = zero; oaccB[ct] = zero; }
    float mregA = -__builtin_inff(), lregA = 0.f;
    float mregB = -__builtin_inff(), lregB = 0.f;
    f32x4 spA0 = zero, spA1 = zero, spB0 = zero, spB1 = zero;

    // K staging: 7 loads/thread (uniform). V staging: 4 (+1 if tid<64 -> wave0:5).
#define ISSUE_K(TILE, BUF) do { \
    const unsigned short* ks_ = kiph + (size_t)(TILE)*BN*DIP; \
    const unsigned short* ms_ = kmxh + (size_t)(TILE)*BN*DKM; \
    unsigned short* ktd_ = smem + (BUF)*8192; \
    unsigned short* kmd_ = smem + 16384 + (BUF)*6144; \
    gload16(ks_ + kto0, ktd_ + tid*8); \
    gload16(ks_ + kto1, ktd_ + (tid+256)*8); \
    gload16(ks_ + kto2, ktd_ + (tid+512)*8); \
    gload16(ks_ + kto3, ktd_ + (tid+768)*8); \
    gload16(ms_ + kmo0, kmd_ + tid*8); \
    gload16(ms_ + kmo1, kmd_ + (tid+256)*8); \
    gload16(ms_ + kmo2, kmd_ + (tid+512)*8); \
} while (0)

#define ISSUE_V(TILE, BUF) do { \
    const unsigned short* vs_ = vh + (TILE)*BN; \
    unsigned short* vtd_ = smem + 28672 + (BUF)*8704; \
    gload16(vs_ + vto0, vtd_ + tid*8); \
    gload16(vs_ + vto1, vtd_ + (tid+256)*8); \
    gload16(vs_ + vto2, vtd_ + (tid+512)*8); \
    gload16(vs_ + vto3, vtd_ + (tid+768)*8); \
    if (tid < 64) gload16(vs_ + vto4, vtd_ + (tid+1024)*8); \
} while (0)

    // softmax + P-write + PV for one q-half
#define SOFTPV(SP0, SP1, MREG, LREG, OACC, PS0, PS1, PRD, VOFF) do { \
    float pm = fmaxf(fmaxf(fmaxf(SP0[0], SP0[1]), fmaxf(SP0[2], SP0[3])), \
                     fmaxf(fmaxf(SP1[0], SP1[1]), fmaxf(SP1[2], SP1[3]))); \
    pm = fmaxf(pm, __shfl_xor(pm, 16, 64)); \
    pm = fmaxf(pm, __shfl_xor(pm, 32, 64)); \
    if (!__all(pm <= MREG + 8.0f)) { \
        float mnew = fmaxf(MREG, pm); \
        float al = fexp2(MREG - mnew); \
        MREG = mnew; \
        LREG *= al; \
        float a0 = __shfl(al, l4*4+0, 64); \
        float a1 = __shfl(al, l4*4+1, 64); \
        float a2 = __shfl(al, l4*4+2, 64); \
        float a3 = __shfl(al, l4*4+3, 64); \
        _Pragma("unroll") \
        for (int ct = 0; ct < 17; ++ct) { \
            OACC[ct][0] *= a0; OACC[ct][1] *= a1; \
            OACC[ct][2] *= a2; OACC[ct][3] *= a3; \
        } \
    } \
    float p0 = fexp2(SP0[0] - MREG), p1 = fexp2(SP0[1] - MREG); \
    float p2 = fexp2(SP0[2] - MREG), p3 = fexp2(SP0[3] - MREG); \
    float p4 = fexp2(SP1[0] - MREG), p5 = fexp2(SP1[1] - MREG); \
    float p6 = fexp2(SP1[2] - MREG), p7 = fexp2(SP1[3] - MREG); \
    LREG += ((p0 + p1) + (p2 + p3)) + ((p4 + p5) + (p6 + p7)); \
    unsigned r01, r23, r45, r67; \
    asm("v_cvt_pk_bf16_f32 %0, %1, %2" : "=v"(r01) : "v"(p0), "v"(p1)); \
    asm("v_cvt_pk_bf16_f32 %0, %1, %2" : "=v"(r23) : "v"(p2), "v"(p3)); \
    asm("v_cvt_pk_bf16_f32 %0, %1, %2" : "=v"(r45) : "v"(p4), "v"(p5)); \
    asm("v_cvt_pk_bf16_f32 %0, %1, %2" : "=v"(r67) : "v"(p6), "v"(p7)); \
    { \
        char* pbp = (char*)smem; \
        *(unsigned*)(pbp + PS0 + 0) = r01; \
        *(unsigned*)(pbp + PS0 + 4) = r23; \
        *(unsigned*)(pbp + PS1 + 0) = r45; \
        *(unsigned*)(pbp + PS1 + 4) = r67; \
    } \
    { \
        bf16x8 pa = *(const bf16x8*)((const char*)smem + PRD); \
        const char* vtb_ = (const char*)smem + 57344 + (VOFF); \
        _Pragma("unroll") \
        for (int ct = 0; ct < 17; ++ct) { \
            bf16x8 bv = *(const bf16x8*)(vtb_ + vlane + ct*1024); \
            OACC[ct] = MFMA16(pa, bv, OACC[ct]); \
        } \
    } \
} while (0)

    ISSUE_K(0, 0);
    #pragma unroll 1
    for (int t = 0; t < NT; ++t) {
        int cur = t & 1;
        if (t < NT-1) {
            ISSUE_K(t+1, cur^1);
            ISSUE_V(t, cur);
            // older loads (K(t), V(t-1)) complete; K(t+1)+V(t) stay in flight
            if (w == 0) asm volatile("s_waitcnt vmcnt(12)" ::: "memory");
            else        asm volatile("s_waitcnt vmcnt(11)" ::: "memory");
        } else {
            ISSUE_V(t, cur);
            if (w == 0) asm volatile("s_waitcnt vmcnt(5)" ::: "memory");
            else        asm volatile("s_waitcnt vmcnt(4)" ::: "memory");
        }
        __builtin_amdgcn_sched_barrier(0);
        __builtin_amdgcn_s_barrier();       // tile t (kt,kmx) + V(t-1) visible to all
        __builtin_amdgcn_sched_barrier(0);

        const char* ktb = (const char*)smem + cur*16384;
        const char* kmb = (const char*)smem + 32768 + cur*12288;
        f32x4 snA0 = zero, snA1 = zero, snB0 = zero, snB1 = zero;
        #pragma unroll
        for (int ks = 0; ks < 8; ++ks) {     // ip+s dims: A-frag read once, used by both q-halves
            int off = (ks & 1) ? (kbO + (ks-1)*64) : (kbE + ks*64);
            bf16x8 a0 = *(const bf16x8*)(ktb + off);
            bf16x8 a1 = *(const bf16x8*)(ktb + off + 8192);
            snA0 = MFMA16(a0, qip0[ks], snA0);
            snB0 = MFMA16(a0, qip1[ks], snB0);
            snA1 = MFMA16(a1, qip0[ks], snA1);
            snB1 = MFMA16(a1, qip1[ks], snB1);
        }
        {   // dist split-precision, dup-block scheme, ct=0
            const char* kk = kmb;
            bf16x8 ka0 = *(const bf16x8*)(kk + mA);
            bf16x8 ka1 = *(const bf16x8*)(kk + mB);
            bf16x8 ka2 = *(const bf16x8*)(kk + mA + 128);
            bf16x8 kb0 = *(const bf16x8*)(kk + mB + 128);
            bf16x8 kb1 = *(const bf16x8*)(kk + mA + 256);
            bf16x8 kb2 = *(const bf16x8*)(kk + mB + 256);
            snA0 = MFMA16(ka0, qdx0[0], snA0);  snB0 = MFMA16(ka0, qdx1[0], snB0);
            snA0 = MFMA16(ka1, qdx0[1], snA0);  snB0 = MFMA16(ka1, qdx1[1], snB0);
            snA0 = MFMA16(ka2, qdx0[2], snA0);  snB0 = MFMA16(ka2, qdx1[2], snB0);
            snA0 = MFMA16(kb0, qdx0[3], snA0);  snB0 = MFMA16(kb0, qdx1[3], snB0);
            snA0 = MFMA16(kb1, qdx0[4], snA0);  snB0 = MFMA16(kb1, qdx1[4], snB0);
            snA0 = MFMA16(kb2, qdx0[5], snA0);  snB0 = MFMA16(kb2, qdx1[5], snB0);
            snA0 = MFMA16(ka0, qdx0[3], snA0);  snB0 = MFMA16(ka0, qdx1[3], snB0);
            snA0 = MFMA16(ka1, qdx0[6], snA0);  snB0 = MFMA16(ka1, qdx1[6], snB0);
            snA0 = MFMA16(kb0, qdx0[0], snA0);  snB0 = MFMA16(kb0, qdx1[0], snB0);
            snA0 = MFMA16(kb1, qdx0[7], snA0);  snB0 = MFMA16(kb1, qdx1[7], snB0);
        }
        {   // ct=1
            const char* kk = kmb + 6144;
            bf16x8 ka0 = *(const bf16x8*)(kk + mA);
            bf16x8 ka1 = *(const bf16x8*)(kk + mB);
            bf16x8 ka2 = *(const bf16x8*)(kk + mA + 128);
            bf16x8 kb0 = *(const bf16x8*)(kk + mB + 128);
            bf16x8 kb1 = *(const bf16x8*)(kk + mA + 256);
            bf16x8 kb2 = *(const bf16x8*)(kk + mB + 256);
            snA1 = MFMA16(ka0, qdx0[0], snA1);  snB1 = MFMA16(ka0, qdx1[0], snB1);
            snA1 = MFMA16(ka1, qdx0[1], snA1);  snB1 = MFMA16(ka1, qdx1[1], snB1);
            snA1 = MFMA16(ka2, qdx0[2], snA1);  snB1 = MFMA16(ka2, qdx1[2], snB1);
            snA1 = MFMA16(kb0, qdx0[3], snA1);  snB1 = MFMA16(kb0, qdx1[3], snB1);
            snA1 = MFMA16(kb1, qdx0[4], snA1);  snB1 = MFMA16(kb1, qdx1[4], snB1);
            snA1 = MFMA16(kb2, qdx0[5], snA1);  snB1 = MFMA16(kb2, qdx1[5], snB1);
            snA1 = MFMA16(ka0, qdx0[3], snA1);  snB1 = MFMA16(ka0, qdx1[3], snB1);
            snA1 = MFMA16(ka1, qdx0[6], snA1);  snB1 = MFMA16(ka1, qdx1[6], snB1);
            snA1 = MFMA16(kb0, qdx0[0], snA1);  snB1 = MFMA16(kb0, qdx1[0], snB1);
            snA1 = MFMA16(kb1, qdx0[7], snA1);  snB1 = MFMA16(kb1, qdx1[7], snB1);
        }
        // softmax + PV of tile t-1 (V in buffer cur^1) — overlaps the QKT above
        if (t > 0) {
            SOFTPV(spA0, spA1, mregA, lregA, oaccA, pA0, pA1, pRA, (cur^1)*17408);
            SOFTPV(spB0, spB1, mregB, lregB, oaccB, pB0, pB1, pRB, (cur^1)*17408);
        }
        spA0 = snA0; spA1 = snA1; spB0 = snB0; spB1 = snB1;
        __builtin_amdgcn_s_barrier();        // all waves done reading recycled buffers
        __builtin_amdgcn_sched_barrier(0);
    }
#undef ISSUE_K
#undef ISSUE_V

    // epilogue: drain V(NT-1), then softmax+PV of last tile
    asm volatile("s_waitcnt vmcnt(0)" ::: "memory");
    __builtin_amdgcn_sched_barrier(0);
    __builtin_amdgcn_s_barrier();
    __builtin_amdgcn_sched_barrier(0);
    SOFTPV(spA0, spA1, mregA, lregA, oaccA, pA0, pA1, pRA, ((NT-1)&1)*17408);
    SOFTPV(spB0, spB1, mregB, lregB, oaccB, pB0, pB1, pRB, ((NT-1)&1)*17408);
#undef SOFTPV

    // finish deferred l, scatter (both q-halves)
    const size_t mv_total = (size_t)HH * NN * 256;
    float lfA = lregA, lfB = lregB;
    lfA += __shfl_xor(lfA, 16, 64);
    lfA += __shfl_xor(lfA, 32, 64);
    lfB += __shfl_xor(lfB, 16, 64);
    lfB += __shfl_xor(lfB, 32, 64);
    #pragma unroll
    for (int j = 0; j < 4; ++j) {
        float invA = 1.0f / __shfl(lfA, l4*4 + j, 64);
        int qA = q0 + w*32 + l4*4 + j;
        float* poA = out + ((size_t)h*NN + qA) * 256 + l15;
        #pragma unroll
        for (int ct = 0; ct < 16; ++ct)
            poA[ct*16] = oaccA[ct][j] * invA;
        out[mv_total + ((size_t)h*NN + qA)*16 + l15] = oaccA[16][j] * invA;

        float invB = 1.0f / __shfl(lfB, l4*4 + j, 64);
        int qB = qA + 16;
        float* poB = out + ((size_t)h*NN + qB) * 256 + l15;
        #pragma unroll
        for (int ct = 0; ct < 16; ++ct)
            poB[ct*16] = oaccB[ct][j] * invB;
        out[mv_total + ((size_t)h*NN + qB)*16 + l15] = oaccB[16][j] * invB;
    }
}

extern "C" void kernel_launch(void* const* d_in, const int* in_sizes, int n_in,
                              void* d_out, int out_size, void* d_ws, size_t ws_size,
                              hipStream_t stream)
{
    const float* q_mv = (const float*)d_in[0];
    const float* k_mv = (const float*)d_in[1];
    const float* v_mv = (const float*)d_in[2];
    const float* q_s  = (const float*)d_in[3];
    const float* k_s  = (const float*)d_in[4];
    const float* v_s  = (const float*)d_in[5];
    const float* basis_q = (const float*)d_in[6];
    const float* basis_k = (const float*)d_in[7];
    float* out = (float*)d_out;

    unsigned short* qip = (unsigned short*)d_ws;                 // [8][4096][256]
    unsigned short* qdx = qip + (size_t)HH*NN*DIP;               // [8][4096][256]
    unsigned short* kip = qdx + (size_t)HH*NN*DDX;               // [8][4096][256]
    unsigned short* kmx = kip + (size_t)HH*NN*DIP;               // [8][4096][192]
    unsigned short* vt  = kmx + (size_t)HH*NN*DKM;               // [8][272][4096]
    // total ws use: 80,740,352 bytes

    // 1/sqrt(304) * log2(e): logits in log2 units -> exp via single v_exp_f32
    const float qscale = 0.08274443827037988f;

    feat_kernel<<<dim3(1024), dim3(256), 0, stream>>>(q_mv, q_s, basis_q, qscale, 1, qip, qdx);
    feat_kernel<<<dim3(1024), dim3(256), 0, stream>>>(k_mv, k_s, basis_k, 1.0f,   0, kip, kmx);
    vtrans_kernel<<<dim3(512), dim3(256), 0, stream>>>(v_mv, v_s, vt);
    attn_kernel<<<dim3(256), dim3(256), 0, stream>>>(qip, qdx, kip, kmx, vt, out);
}

// Round 11
// 511.217 us; speedup vs baseline: 1.1273x; 1.1273x over previous
//
#include <hip/hip_runtime.h>
#include <math.h>

typedef short bf16x8 __attribute__((ext_vector_type(8)));
typedef float f32x4 __attribute__((ext_vector_type(4)));

#define HH 8
#define NN 4096
#define DIP 256   // ip(240) + s(16), no pad
#define DDX 256   // qdx: [hi|hi | mid|lo | mid32-47+16z | hi32-47+16z]
#define DKM 192   // kmx: [mid | lo | hi | hi]
#define DV 272
#define BN 32
#define NT (NN/BN)

typedef const __attribute__((address_space(1))) unsigned int* gp_t;
typedef __attribute__((address_space(3))) unsigned int* lp_t;
__device__ __forceinline__ void gload16(const void* g, void* l) {
    __builtin_amdgcn_global_load_lds((gp_t)g, (lp_t)l, 16, 0, 0);
}

__device__ __forceinline__ unsigned short f2bf(float f) {
    unsigned int u = __float_as_uint(f);
    u = (u + 0x7fffu + ((u >> 16) & 1u)) >> 16;   // RNE
    return (unsigned short)u;
}
__device__ __forceinline__ float bf2f(unsigned short h) {
    return __uint_as_float(((unsigned int)h) << 16);
}
__device__ __forceinline__ float fexp2(float x) {   // 2^x, single v_exp_f32
    float r;
    asm("v_exp_f32 %0, %1" : "=v"(r) : "v"(x));
    return r;
}

#define MFMA16(A,B,C) __builtin_amdgcn_mfma_f32_16x16x32_bf16((A),(B),(C),0,0,0)

// ---- stage 1a: features. fip[256] = ip+s. fdx: Q-mode 256 cols / K-mode 192 cols ----
__global__ void feat_kernel(const float* __restrict__ mv,
                            const float* __restrict__ sv,
                            const float* __restrict__ basis,
                            float scale, int qmode,
                            unsigned short* __restrict__ fip,
                            unsigned short* __restrict__ fdx)
{
    __shared__ float sb[150];
    int t = threadIdx.x;
    if (t < 150) sb[t] = basis[t];
    __syncthreads();
    int row = blockIdx.x * 32 + (t >> 3);   // (h*4096+n)
    int c = t & 7;
    const float* m = mv + (size_t)row * 256 + c * 32;
    float f[32];
    #pragma unroll
    for (int i = 0; i < 8; ++i) {
        float4 v = ((const float4*)m)[i];
        f[i*4+0] = v.x; f[i*4+1] = v.y; f[i*4+2] = v.z; f[i*4+3] = v.w;
    }
    unsigned short* ip = fip + (size_t)row * DIP;
    unsigned short* dx = fdx + (size_t)row * (qmode ? DDX : DKM);
    #pragma unroll
    for (int j = 0; j < 30; ++j)
        ip[c*30 + j] = f2bf(f[1+j] * scale);
    if (c < 2) {
        #pragma unroll
        for (int i = 0; i < 8; ++i)
            ip[240 + c*8 + i] = f2bf(sv[(size_t)row*16 + c*8 + i] * scale);
    }
    float nn = 1.0f / sqrtf(f[5]*f[5] + 0.001f);
    float tn[5];
    #pragma unroll
    for (int x = 0; x < 5; ++x) tn[x] = f[1+x] * nn;
    #pragma unroll
    for (int z = 0; z < 6; ++z) {
        float acc = 0.f;
        #pragma unroll
        for (int x = 0; x < 5; ++x) {
            #pragma unroll
            for (int y = 0; y < 5; ++y)
                acc = fmaf(sb[(x*5+y)*6 + z] * tn[x], tn[y], acc);
        }
        acc *= scale;
        unsigned short hi = f2bf(acc);
        float r1 = acc - bf2f(hi);
        unsigned short mi = f2bf(r1);
        float r2 = r1 - bf2f(mi);
        unsigned short lo = f2bf(r2);
        int cz = c*6 + z;
        if (qmode) {
            dx[cz]      = hi;  dx[48 + cz]  = hi;
            dx[96 + cz] = mi;  dx[144 + cz] = lo;
            if (cz < 16) { dx[208 + cz] = 0; dx[240 + cz] = 0; }
            if (cz >= 32) { dx[160 + cz] = mi; dx[192 + cz] = hi; }
        } else {
            dx[cz]      = mi;  dx[48 + cz]  = lo;
            dx[96 + cz] = hi;  dx[144 + cz] = hi;
        }
    }
}

// ---- stage 1b: V -> transposed bf16 [8][272][4096] ----
__global__ void vtrans_kernel(const float* __restrict__ vmv,
                              const float* __restrict__ vs,
                              unsigned short* __restrict__ dst)
{
    __shared__ unsigned short tile[64][DV];
    int blk = blockIdx.x;
    int h = blk >> 6;
    int n0 = (blk & 63) << 6;
    int t = threadIdx.x;
    #pragma unroll
    for (int it = 0; it < 16; ++it) {
        int v = t + it*256;
        int r = v >> 6;
        int sg = v & 63;
        float4 x = *(const float4*)(vmv + ((size_t)(h*NN + n0 + r))*256 + sg*4);
        tile[r][sg*4+0] = f2bf(x.x);
        tile[r][sg*4+1] = f2bf(x.y);
        tile[r][sg*4+2] = f2bf(x.z);
        tile[r][sg*4+3] = f2bf(x.w);
    }
    #pragma unroll
    for (int it = 0; it < 4; ++it) {
        int v = t + it*256;
        int r = v >> 4;
        int si = v & 15;
        tile[r][256 + si] = f2bf(vs[((size_t)(h*NN + n0 + r))*16 + si]);
    }
    __syncthreads();
    #pragma unroll
    for (int it = 0; it < 17; ++it) {
        int v = t + it*256;
        int dd = v >> 4;
        int sg = v & 15;
        ushort4 o;
        o.x = tile[sg*4+0][dd];
        o.y = tile[sg*4+1][dd];
        o.z = tile[sg*4+2][dd];
        o.w = tile[sg*4+3][dd];
        *(ushort4*)(dst + ((size_t)(h*DV + dd))*NN + n0 + sg*4) = o;
    }
}

// ---- stage 2: flash attention, pair-split (keys for QKT, dims for PV), 8 waves ----
__global__ __launch_bounds__(512, 1)
void attn_kernel(const unsigned short* __restrict__ Qip,
                 const unsigned short* __restrict__ Qdx,
                 const unsigned short* __restrict__ Kip,
                 const unsigned short* __restrict__ Kmx,
                 const unsigned short* __restrict__ Vt,
                 float* __restrict__ out)
{
    // LDS (ush): kt 2x8192 [0,16384) | kmx 2x6144 [16384,28672) | vt 3x8704 [28672,54784)
    //            pb 4096 [54784,58880) | mx 512 [58880,59392)   — 118,784 B total
    __shared__ __align__(128) unsigned short smem[59392];

    int blk = blockIdx.x;
    int sbk = ((blk & 7) << 5) | (blk >> 3);   // grid 256, bijective XCD swizzle; XCD x = head x
    int h = sbk >> 5;
    int q0 = (sbk & 31) * 128;
    int tid = threadIdx.x;
    int w = tid >> 6;
    int g  = w & 3;        // q-group: rows [q0+g*32, q0+g*32+32)
    int kh = w >> 2;       // key-half owner: 0 -> keys 0-15, 1 -> keys 16-31
    int lane = tid & 63;
    int l15 = lane & 15;
    int l4 = lane >> 4;
    int l7l = l15 & 3;
    int l7h = (l15 >> 2) & 1;
    int swq = (l15 ^ (l15 >> 2)) & 3;          // P-region swizzle for q-row l15 (same for +16)

    // Q fragments, two 16-row halves (B-operand: col=q=l15)
    const unsigned short* qipr = Qip + (size_t)(h*NN + q0 + g*32 + l15) * DIP + l4*8;
    const unsigned short* qdxr = Qdx + (size_t)(h*NN + q0 + g*32 + l15) * DDX + l4*8;
    bf16x8 qip0[8], qip1[8], qdx0[8], qdx1[8];
    #pragma unroll
    for (int ks = 0; ks < 8; ++ks) {
        qip0[ks] = *(const bf16x8*)(qipr + ks*32);
        qip1[ks] = *(const bf16x8*)(qipr + 16*DIP + ks*32);
        qdx0[ks] = *(const bf16x8*)(qdxr + ks*32);
        qdx1[ks] = *(const bf16x8*)(qdxr + 16*DDX + ks*32);
    }

    // LDS read bases (bytes)
    int cl16 = (l4 ^ l7l) * 16;
    int kbE = l15*512 + cl16 + l7h*64;
    int kbO = l15*512 + cl16 + 64 - l7h*64;
    int mA  = l15*384 + cl16 + l7h*64;
    int mB  = l15*384 + cl16 + 64 - l7h*64;
    int vlane = (l15>>1)*128 + (((((l15&1)<<2) | l4) ^ (l15>>1)) << 4);
    // P region: per group 2048 B, row=q (32 rows x 64 B), 16B-seg XOR-swizzled by swq
    int pw = 109568 + g*2048 + l15*64 + ((((kh<<1) | (l4>>1)) ^ swq) << 4) + (l4&1)*8;
    int pr = 109568 + g*2048 + l15*64 + ((l4 ^ swq) << 4);
    // mx region: per group 256 B = [2 kh][2 half][16 q] f32
    int mxw = 117760 + g*256 + kh*128 + l15*4;
    int mxr = 117760 + g*256 + (kh^1)*128 + l15*4;

    // DMA source offsets (ush), loop-invariant (512-thread slot maps, r8-verified)
    int kt0s, kt1s, km0s, km1vt, vt1s, vt2s;
#define KTFL(SLOT, DST) { int r_ = (SLOT) >> 5, fp_ = (SLOT) & 31; \
    int fl_ = (fp_ & 24) | ((((fp_>>2)&1) ^ ((r_>>2)&1)) << 2) | ((fp_&3) ^ (r_&3)); \
    DST = r_*DIP + fl_*8; }
#define KMFL(SLOT, DST) { int r_ = (SLOT)/24, fp_ = (SLOT)%24; \
    int g_ = fp_>>3, po_ = fp_&7; \
    int pl_ = ((((po_>>2)&1) ^ ((r_>>2)&1)) << 2) | ((po_&3) ^ (r_&3)); \
    DST = r_*DKM + (g_*8 + pl_)*8; }
#define VTF(SLOT, DST) { int ch_ = (SLOT) >> 3, ws_ = (SLOT) & 7; int lw_ = ws_ ^ (ch_&7); \
    DST = (ch_*2 + (lw_>>2))*NN + (lw_&3)*8; }
    KTFL(tid, kt0s) KTFL(tid+512, kt1s)
    KMFL(tid, km0s)
    if (tid < 256) { KMFL(tid+512, km1vt) } else { VTF(tid-256, km1vt) }
    VTF(tid+256, vt1s)
    VTF(tid+768, vt2s)
#undef KTFL
#undef KMFL
#undef VTF

    const unsigned short* kiph = Kip + (size_t)h*NN*DIP;
    const unsigned short* kmxh = Kmx + (size_t)h*NN*DKM;
    const unsigned short* vh   = Vt  + (size_t)h*DV*NN;

    f32x4 zero = {0.f, 0.f, 0.f, 0.f};
    f32x4 oacc[9][2];                   // own 9|8 dim-tiles x 2 q-halves
    #pragma unroll
    for (int i = 0; i < 9; ++i) { oacc[i][0] = zero; oacc[i][1] = zero; }
    float m0 = -__builtin_inff(), m1 = -__builtin_inff();
    float l0 = 0.f, l1 = 0.f;

#define ISSUE(TILE, KBUF, VOFF) do { \
    const unsigned short* ks_ = kiph + (size_t)(TILE)*BN*DIP; \
    const unsigned short* ms_ = kmxh + (size_t)(TILE)*BN*DKM; \
    const unsigned short* vs_ = vh + (TILE)*BN; \
    unsigned short* ktd_ = smem + (KBUF)*8192; \
    unsigned short* kmd_ = smem + 16384 + (KBUF)*6144; \
    unsigned short* vtd_ = smem + 28672 + (VOFF); \
    gload16(ks_ + kt0s, ktd_ + tid*8); \
    gload16(ks_ + kt1s, ktd_ + (tid+512)*8); \
    gload16(ms_ + km0s, kmd_ + tid*8); \
    if (tid < 256) gload16(ms_ + km1vt, kmd_ + (512+tid)*8); \
    else           gload16(vs_ + km1vt, vtd_ + (tid-256)*8); \
    gload16(vs_ + vt1s, vtd_ + (tid+256)*8); \
    if (tid < 320) gload16(vs_ + vt2s, vtd_ + (tid+768)*8); \
} while (0)

    ISSUE(0, 0, 0);
    int vrd = 0, vwr = 8704;           // vt triple-buffer ush offsets
    #pragma unroll 1
    for (int t = 0; t < NT; ++t) {
        int cur = t & 1;
        if (t < NT-1) {
            ISSUE(t+1, cur^1, vwr);
            if (w < 5) asm volatile("s_waitcnt vmcnt(6)" ::: "memory");
            else       asm volatile("s_waitcnt vmcnt(5)" ::: "memory");
        } else {
            asm volatile("s_waitcnt vmcnt(0)" ::: "memory");
        }
        __builtin_amdgcn_sched_barrier(0);
        __builtin_amdgcn_s_barrier();       // BAR1: tile t staged
        __builtin_amdgcn_sched_barrier(0);

        // ---- QKT: own 16 keys x 32 q ----
        const char* ktb = (const char*)smem + cur*16384 + kh*8192;
        const char* kmb = (const char*)smem + 32768 + cur*12288 + kh*6144;
        f32x4 sn0 = zero, sn1 = zero;
        __builtin_amdgcn_s_setprio(1);
        #pragma unroll
        for (int ks = 0; ks < 8; ++ks) {
            int off = (ks & 1) ? (kbO + (ks-1)*64) : (kbE + ks*64);
            bf16x8 a = *(const bf16x8*)(ktb + off);
            sn0 = MFMA16(a, qip0[ks], sn0);
            sn1 = MFMA16(a, qip1[ks], sn1);
        }
        {   // dist split-precision (dup-block)
            bf16x8 ka0 = *(const bf16x8*)(kmb + mA);
            bf16x8 ka1 = *(const bf16x8*)(kmb + mB);
            bf16x8 ka2 = *(const bf16x8*)(kmb + mA + 128);
            bf16x8 kb0 = *(const bf16x8*)(kmb + mB + 128);
            bf16x8 kb1 = *(const bf16x8*)(kmb + mA + 256);
            bf16x8 kb2 = *(const bf16x8*)(kmb + mB + 256);
            sn0 = MFMA16(ka0, qdx0[0], sn0);  sn1 = MFMA16(ka0, qdx1[0], sn1);
            sn0 = MFMA16(ka1, qdx0[1], sn0);  sn1 = MFMA16(ka1, qdx1[1], sn1);
            sn0 = MFMA16(ka2, qdx0[2], sn0);  sn1 = MFMA16(ka2, qdx1[2], sn1);
            sn0 = MFMA16(kb0, qdx0[3], sn0);  sn1 = MFMA16(kb0, qdx1[3], sn1);
            sn0 = MFMA16(kb1, qdx0[4], sn0);  sn1 = MFMA16(kb1, qdx1[4], sn1);
            sn0 = MFMA16(kb2, qdx0[5], sn0);  sn1 = MFMA16(kb2, qdx1[5], sn1);
            sn0 = MFMA16(ka0, qdx0[3], sn0);  sn1 = MFMA16(ka0, qdx1[3], sn1);
            sn0 = MFMA16(ka1, qdx0[6], sn0);  sn1 = MFMA16(ka1, qdx1[6], sn1);
            sn0 = MFMA16(kb0, qdx0[0], sn0);  sn1 = MFMA16(kb0, qdx1[0], sn1);
            sn0 = MFMA16(kb1, qdx0[7], sn0);  sn1 = MFMA16(kb1, qdx1[7], sn1);
        }
        __builtin_amdgcn_s_setprio(0);

        // ---- partial max over own 16 keys, exchange with partner ----
        float pm0 = fmaxf(fmaxf(sn0[0], sn0[1]), fmaxf(sn0[2], sn0[3]));
        float pm1 = fmaxf(fmaxf(sn1[0], sn1[1]), fmaxf(sn1[2], sn1[3]));
        pm0 = fmaxf(pm0, __shfl_xor(pm0, 16, 64));
        pm0 = fmaxf(pm0, __shfl_xor(pm0, 32, 64));
        pm1 = fmaxf(pm1, __shfl_xor(pm1, 16, 64));
        pm1 = fmaxf(pm1, __shfl_xor(pm1, 32, 64));
        if (l4 == 0) {
            *(float*)((char*)smem + mxw)      = pm0;
            *(float*)((char*)smem + mxw + 64) = pm1;
        }
        asm volatile("s_waitcnt lgkmcnt(0)" ::: "memory");
        __builtin_amdgcn_sched_barrier(0);
        __builtin_amdgcn_s_barrier();       // BAR2: pm visible
        __builtin_amdgcn_sched_barrier(0);
        float pc0 = fmaxf(pm0, *(const float*)((const char*)smem + mxr));
        float pc1 = fmaxf(pm1, *(const float*)((const char*)smem + mxr + 64));

        // shared-m online softmax (identical trajectory on both pair waves)
        bool no0 = __all(pc0 <= m0 + 8.0f);
        bool no1 = __all(pc1 <= m1 + 8.0f);
        if (!(no0 && no1)) {
            float mn0 = fmaxf(m0, pc0), mn1 = fmaxf(m1, pc1);
            float al0 = fexp2(m0 - mn0), al1 = fexp2(m1 - mn1);   // 0 on first tile
            m0 = mn0; m1 = mn1;
            l0 *= al0; l1 *= al1;
            float a00 = __shfl(al0, l4*4+0, 64), a01 = __shfl(al0, l4*4+1, 64);
            float a02 = __shfl(al0, l4*4+2, 64), a03 = __shfl(al0, l4*4+3, 64);
            float a10 = __shfl(al1, l4*4+0, 64), a11 = __shfl(al1, l4*4+1, 64);
            float a12 = __shfl(al1, l4*4+2, 64), a13 = __shfl(al1, l4*4+3, 64);
            #pragma unroll
            for (int i = 0; i < 9; ++i) {
                oacc[i][0][0] *= a00; oacc[i][0][1] *= a01;
                oacc[i][0][2] *= a02; oacc[i][0][3] *= a03;
                oacc[i][1][0] *= a10; oacc[i][1][1] *= a11;
                oacc[i][1][2] *= a12; oacc[i][1][3] *= a13;
            }
        }
        float p0 = fexp2(sn0[0] - m0), p1 = fexp2(sn0[1] - m0);
        float p2 = fexp2(sn0[2] - m0), p3 = fexp2(sn0[3] - m0);
        float p4 = fexp2(sn1[0] - m1), p5 = fexp2(sn1[1] - m1);
        float p6 = fexp2(sn1[2] - m1), p7 = fexp2(sn1[3] - m1);
        l0 += (p0 + p1) + (p2 + p3);
        l1 += (p4 + p5) + (p6 + p7);
        unsigned r01, r23, r45, r67;
        asm("v_cvt_pk_bf16_f32 %0, %1, %2" : "=v"(r01) : "v"(p0), "v"(p1));
        asm("v_cvt_pk_bf16_f32 %0, %1, %2" : "=v"(r23) : "v"(p2), "v"(p3));
        asm("v_cvt_pk_bf16_f32 %0, %1, %2" : "=v"(r45) : "v"(p4), "v"(p5));
        asm("v_cvt_pk_bf16_f32 %0, %1, %2" : "=v"(r67) : "v"(p6), "v"(p7));
        {
            char* pbp = (char*)smem;
            *(unsigned*)(pbp + pw + 0)      = r01;
            *(unsigned*)(pbp + pw + 4)      = r23;
            *(unsigned*)(pbp + pw + 1024)     = r45;
            *(unsigned*)(pbp + pw + 1024 + 4) = r67;
        }
        asm volatile("s_waitcnt lgkmcnt(0)" ::: "memory");
        __builtin_amdgcn_sched_barrier(0);
        __builtin_amdgcn_s_barrier();       // BAR3: full P (both key-halves) visible
        __builtin_amdgcn_sched_barrier(0);

        // ---- PV: own 9|8 dim-tiles, both q-halves, full 32 keys ----
        {
            bf16x8 pa0 = *(const bf16x8*)((const char*)smem + pr);
            bf16x8 pa1 = *(const bf16x8*)((const char*)smem + pr + 1024);
            const char* vtb = (const char*)smem + 57344 + 2*vrd;
            __builtin_amdgcn_s_setprio(1);
            #pragma unroll
            for (int i = 0; i < 9; ++i) {
                if (i < 8 || kh == 0) {
                    int ct = kh*9 + i;
                    bf16x8 bv = *(const bf16x8*)(vtb + vlane + ct*1024);
                    oacc[i][0] = MFMA16(pa0, bv, oacc[i][0]);
                    oacc[i][1] = MFMA16(pa1, bv, oacc[i][1]);
                }
            }
            __builtin_amdgcn_s_setprio(0);
        }
        vrd = vwr;
        vwr = (vwr == 17408) ? 0 : vwr + 8704;
    }
#undef ISSUE

    // ---- epilogue: combine partner l, scatter own dim-range ----
    l0 += __shfl_xor(l0, 16, 64);
    l0 += __shfl_xor(l0, 32, 64);
    l1 += __shfl_xor(l1, 16, 64);
    l1 += __shfl_xor(l1, 32, 64);
    __builtin_amdgcn_s_barrier();           // all waves past last mx read
    if (l4 == 0) {
        *(float*)((char*)smem + mxw)      = l0;
        *(float*)((char*)smem + mxw + 64) = l1;
    }
    asm volatile("s_waitcnt lgkmcnt(0)" ::: "memory");
    __builtin_amdgcn_sched_barrier(0);
    __builtin_amdgcn_s_barrier();
    __builtin_amdgcn_sched_barrier(0);
    float lt0 = l0 + *(const float*)((const char*)smem + mxr);
    float lt1 = l1 + *(const float*)((const char*)smem + mxr + 64);

    const size_t mv_total = (size_t)HH * NN * 256;
    #pragma unroll
    for (int j = 0; j < 4; ++j) {
        float inv0 = 1.0f / __shfl(lt0, l4*4 + j, 64);
        float inv1 = 1.0f / __shfl(lt1, l4*4 + j, 64);
        int qA = q0 + g*32 + l4*4 + j;
        int qB = qA + 16;
        float* poA = out + ((size_t)h*NN + qA) * 256 + l15;
        float* poB = out + ((size_t)h*NN + qB) * 256 + l15;
        #pragma unroll
        for (int i = 0; i < 9; ++i) {
            if (i < 8 || kh == 0) {
                int ct = kh*9 + i;
                if (ct < 16) {
                    poA[ct*16] = oacc[i][0][j] * inv0;
                    poB[ct*16] = oacc[i][1][j] * inv1;
                } else {
                    out[mv_total + ((size_t)h*NN + qA)*16 + l15] = oacc[i][0][j] * inv0;
                    out[mv_total + ((size_t)h*NN + qB)*16 + l15] = oacc[i][1][j] * inv1;
                }
            }
        }
    }
}

extern "C" void kernel_launch(void* const* d_in, const int* in_sizes, int n_in,
                              void* d_out, int out_size, void* d_ws, size_t ws_size,
                              hipStream_t stream)
{
    const float* q_mv = (const float*)d_in[0];
    const float* k_mv = (const float*)d_in[1];
    const float* v_mv = (const float*)d_in[2];
    const float* q_s  = (const float*)d_in[3];
    const float* k_s  = (const float*)d_in[4];
    const float* v_s  = (const float*)d_in[5];
    const float* basis_q = (const float*)d_in[6];
    const float* basis_k = (const float*)d_in[7];
    float* out = (float*)d_out;

    unsigned short* qip = (unsigned short*)d_ws;                 // [8][4096][256]
    unsigned short* qdx = qip + (size_t)HH*NN*DIP;               // [8][4096][256]
    unsigned short* kip = qdx + (size_t)HH*NN*DDX;               // [8][4096][256]
    unsigned short* kmx = kip + (size_t)HH*NN*DIP;               // [8][4096][192]
    unsigned short* vt  = kmx + (size_t)HH*NN*DKM;               // [8][272][4096]
    // total ws use: 80,740,352 bytes

    // 1/sqrt(304) * log2(e): logits in log2 units -> exp via single v_exp_f32
    const float qscale = 0.08274443827037988f;

    feat_kernel<<<dim3(1024), dim3(256), 0, stream>>>(q_mv, q_s, basis_q, qscale, 1, qip, qdx);
    feat_kernel<<<dim3(1024), dim3(256), 0, stream>>>(k_mv, k_s, basis_k, 1.0f,   0, kip, kmx);
    vtrans_kernel<<<dim3(512), dim3(256), 0, stream>>>(v_mv, v_s, vt);
    attn_kernel<<<dim3(256), dim3(512), 0, stream>>>(qip, qdx, kip, kmx, vt, out);
}

// Round 12
// 280.568 us; speedup vs baseline: 2.0540x; 1.8221x over previous
//
#include <hip/hip_runtime.h>
#include <math.h>

typedef short bf16x8 __attribute__((ext_vector_type(8)));
typedef float f32x4 __attribute__((ext_vector_type(4)));
typedef int   i32x4 __attribute__((ext_vector_type(4)));

#define HH 8
#define NN 4096
#define DIP 256   // ip(240) + s(16) as int8, no pad
#define DDX 256   // qdx bf16: [hi|hi | mid|lo | mid32-47+16z | hi32-47+16z]
#define DKM 192   // kmx bf16: [mid | lo | hi | hi]
#define DV 272
#define BN 32
#define NT (NN/BN)

typedef const __attribute__((address_space(1))) unsigned int* gp_t;
typedef __attribute__((address_space(3))) unsigned int* lp_t;
__device__ __forceinline__ void gload16(const void* g, void* l) {
    __builtin_amdgcn_global_load_lds((gp_t)g, (lp_t)l, 16, 0, 0);
}

__device__ __forceinline__ unsigned short f2bf(float f) {
    unsigned int u = __float_as_uint(f);
    u = (u + 0x7fffu + ((u >> 16) & 1u)) >> 16;   // RNE
    return (unsigned short)u;
}
__device__ __forceinline__ float bf2f(unsigned short h) {
    return __uint_as_float(((unsigned int)h) << 16);
}
__device__ __forceinline__ float fexp2(float x) {   // 2^x, single v_exp_f32
    float r;
    asm("v_exp_f32 %0, %1" : "=v"(r) : "v"(x));
    return r;
}
__device__ __forceinline__ signed char q8(float x) {  // i8 quant, scale 127/6 (±6 sigma)
    int v = __float2int_rn(x * 21.1666667f);
    v = v < -127 ? -127 : (v > 127 ? 127 : v);
    return (signed char)v;
}

#define MFMA16(A,B,C) __builtin_amdgcn_mfma_f32_16x16x32_bf16((A),(B),(C),0,0,0)
#define MFMAI8(A,B,C) __builtin_amdgcn_mfma_i32_16x16x64_i8((A),(B),(C),0,0,0)

// ---- stage 1a: features. fip[256] = ip+s as i8. fdx bf16: Q-mode 256 / K-mode 192 ----
__global__ void feat_kernel(const float* __restrict__ mv,
                            const float* __restrict__ sv,
                            const float* __restrict__ basis,
                            float scale, int qmode,
                            signed char* __restrict__ fip,
                            unsigned short* __restrict__ fdx)
{
    __shared__ float sb[150];
    int t = threadIdx.x;
    if (t < 150) sb[t] = basis[t];
    __syncthreads();
    int row = blockIdx.x * 32 + (t >> 3);   // (h*4096+n)
    int c = t & 7;
    const float* m = mv + (size_t)row * 256 + c * 32;
    float f[32];
    #pragma unroll
    for (int i = 0; i < 8; ++i) {
        float4 v = ((const float4*)m)[i];
        f[i*4+0] = v.x; f[i*4+1] = v.y; f[i*4+2] = v.z; f[i*4+3] = v.w;
    }
    signed char* ip = fip + (size_t)row * DIP;
    unsigned short* dx = fdx + (size_t)row * (qmode ? DDX : DKM);
    #pragma unroll
    for (int j = 0; j < 30; ++j)
        ip[c*30 + j] = q8(f[1+j]);
    if (c < 2) {
        #pragma unroll
        for (int i = 0; i < 8; ++i)
            ip[240 + c*8 + i] = q8(sv[(size_t)row*16 + c*8 + i]);
    }
    float nn = 1.0f / sqrtf(f[5]*f[5] + 0.001f);
    float tn[5];
    #pragma unroll
    for (int x = 0; x < 5; ++x) tn[x] = f[1+x] * nn;
    #pragma unroll
    for (int z = 0; z < 6; ++z) {
        float acc = 0.f;
        #pragma unroll
        for (int x = 0; x < 5; ++x) {
            #pragma unroll
            for (int y = 0; y < 5; ++y)
                acc = fmaf(sb[(x*5+y)*6 + z] * tn[x], tn[y], acc);
        }
        acc *= scale;
        unsigned short hi = f2bf(acc);
        float r1 = acc - bf2f(hi);
        unsigned short mi = f2bf(r1);
        float r2 = r1 - bf2f(mi);
        unsigned short lo = f2bf(r2);
        int cz = c*6 + z;
        if (qmode) {
            dx[cz]      = hi;  dx[48 + cz]  = hi;
            dx[96 + cz] = mi;  dx[144 + cz] = lo;
            if (cz < 16) { dx[208 + cz] = 0; dx[240 + cz] = 0; }
            if (cz >= 32) { dx[160 + cz] = mi; dx[192 + cz] = hi; }
        } else {
            dx[cz]      = mi;  dx[48 + cz]  = lo;
            dx[96 + cz] = hi;  dx[144 + cz] = hi;
        }
    }
}

// ---- stage 1b: V -> transposed bf16 [8][272][4096] ----
__global__ void vtrans_kernel(const float* __restrict__ vmv,
                              const float* __restrict__ vs,
                              unsigned short* __restrict__ dst)
{
    __shared__ unsigned short tile[64][DV];
    int blk = blockIdx.x;
    int h = blk >> 6;
    int n0 = (blk & 63) << 6;
    int t = threadIdx.x;
    #pragma unroll
    for (int it = 0; it < 16; ++it) {
        int v = t + it*256;
        int r = v >> 6;
        int sg = v & 63;
        float4 x = *(const float4*)(vmv + ((size_t)(h*NN + n0 + r))*256 + sg*4);
        tile[r][sg*4+0] = f2bf(x.x);
        tile[r][sg*4+1] = f2bf(x.y);
        tile[r][sg*4+2] = f2bf(x.z);
        tile[r][sg*4+3] = f2bf(x.w);
    }
    #pragma unroll
    for (int it = 0; it < 4; ++it) {
        int v = t + it*256;
        int r = v >> 4;
        int si = v & 15;
        tile[r][256 + si] = f2bf(vs[((size_t)(h*NN + n0 + r))*16 + si]);
    }
    __syncthreads();
    #pragma unroll
    for (int it = 0; it < 17; ++it) {
        int v = t + it*256;
        int dd = v >> 4;
        int sg = v & 15;
        ushort4 o;
        o.x = tile[sg*4+0][dd];
        o.y = tile[sg*4+1][dd];
        o.z = tile[sg*4+2][dd];
        o.w = tile[sg*4+3][dd];
        *(ushort4*)(dst + ((size_t)(h*DV + dd))*NN + n0 + sg*4) = o;
    }
}

// ---- stage 2: flash attention, r8 structure + i8 ip-QKT ----
__global__ __launch_bounds__(512, 1)
void attn_kernel(const signed char*    __restrict__ Qip,
                 const unsigned short* __restrict__ Qdx,
                 const signed char*    __restrict__ Kip,
                 const unsigned short* __restrict__ Kmx,
                 const unsigned short* __restrict__ Vt,
                 float* __restrict__ out)
{
    // bytes: kt 2x8192 [0,16384) | kmx 2x12288 [16384,40960) | vt 2x17408 [40960,75776) | pb 8192 [75776,83968)
    __shared__ __align__(128) unsigned short smem[41984];   // 83,968 B

    int blk = blockIdx.x;
    int sbk = ((blk & 7) << 5) | (blk >> 3);   // grid 256, bijective XCD swizzle; XCD x = head x
    int h = sbk >> 5;
    int q0 = (sbk & 31) * 128;
    int tid = threadIdx.x;
    int w = tid >> 6;
    int lane = tid & 63;
    int l15 = lane & 15;
    int l4 = lane >> 4;
    int l7l = l15 & 3;
    int l7h = (l15 >> 2) & 1;
    int x7 = l15 & 7;

    // Q ip fragments: i8, B-operand (col=q=l15, k=(l>>4)*16+e), 4 K=64 steps
    const signed char* qipr = Qip + (size_t)(h*NN + q0 + w*16 + l15) * DIP + l4*16;
    i32x4 qip[4];
    #pragma unroll
    for (int s = 0; s < 4; ++s) qip[s] = *(const i32x4*)(qipr + s*64);
    // Q dist fragments: bf16 (dup-block scheme)
    const unsigned short* qdxr = Qdx + (size_t)(h*NN + q0 + w*16 + l15) * DDX + l4*8;
    bf16x8 qdx[8];
    #pragma unroll
    for (int ks = 0; ks < 8; ++ks) qdx[ks] = *(const bf16x8*)(qdxr + ks*32);

    // LDS read bases (bytes)
    int cl16 = (l4 ^ l7l) * 16;
    int mA  = l15*384 + cl16 + l7h*64;
    int mB  = l15*384 + cl16 + 64 - l7h*64;
    int vlane = (l15>>1)*128 + (((((l15&1)<<2) | l4) ^ (l15>>1)) << 4);
    int pbR = 75776 + w*1024 + l15*64;
    int pSeg0 = pbR + ((((l4>>1)    ) ^ l7l) << 4) + (l4&1)*8;
    int pSeg1 = pbR + ((((l4>>1) + 2) ^ l7l) << 4) + (l4&1)*8;
    int pRd   = pbR + ((l4 ^ l7l) << 4);
    // i8 kt read offsets: row=key (l15 within half), logical seg = s*4+l4, phys = seg^(row&7)
    int kti[4];
    #pragma unroll
    for (int s = 0; s < 4; ++s)
        kti[s] = l15*256 + (((s*4 + l4) ^ x7) << 4);

    // DMA source offsets, loop-invariant
    // kt: 512 slots x 16B (32 rows x 16 segs), swizzled source -> linear LDS
    int kt8s;
    { int r_ = tid >> 4, sg_ = tid & 15;
      kt8s = r_*256 + ((sg_ ^ (r_ & 7)) << 4); }          // bytes
    int km0s, km1vt, vt1s, vt2s;
#define KMFL(SLOT, DST) { int r_ = (SLOT)/24, fp_ = (SLOT)%24; \
    int g_ = fp_>>3, po_ = fp_&7; \
    int pl_ = ((((po_>>2)&1) ^ ((r_>>2)&1)) << 2) | ((po_&3) ^ (r_&3)); \
    DST = r_*DKM + (g_*8 + pl_)*8; }
#define VTF(SLOT, DST) { int ch_ = (SLOT) >> 3, ws_ = (SLOT) & 7; int lw_ = ws_ ^ (ch_&7); \
    DST = (ch_*2 + (lw_>>2))*NN + (lw_&3)*8; }
    KMFL(tid, km0s)
    if (tid < 256) { KMFL(tid+512, km1vt) } else { VTF(tid-256, km1vt) }
    VTF(tid+256, vt1s)
    VTF(tid+768, vt2s)
#undef KMFL
#undef VTF

    const signed char*    kiph = Kip + (size_t)h*NN*DIP;
    const unsigned short* kmxh = Kmx + (size_t)h*NN*DKM;
    const unsigned short* vh   = Vt  + (size_t)h*DV*NN;

    f32x4 zero = {0.f, 0.f, 0.f, 0.f};
    i32x4 zi = {0, 0, 0, 0};
    f32x4 oacc[17];
    #pragma unroll
    for (int ct = 0; ct < 17; ++ct) oacc[ct] = zero;
    float mreg = -__builtin_inff();
    float lreg = 0.f;
    // dequant: qscale(log2e) * (6/127)^2
    const float F = 0.08274443827037988f * (6.0f/127.0f) * (6.0f/127.0f);

    // per-wave DMA counts: waves 0-4 issue 5, waves 5-7 issue 4
#define ISSUE(TILE, BUF) do { \
    const signed char* ks_ = kiph + (size_t)(TILE)*BN*DIP; \
    const unsigned short* ms_ = kmxh + (size_t)(TILE)*BN*DKM; \
    const unsigned short* vs_ = vh + (TILE)*BN; \
    char* ktd_ = (char*)smem + (BUF)*8192; \
    unsigned short* kmd_ = smem + 8192 + (BUF)*6144; \
    unsigned short* vtd_ = smem + 20480 + (BUF)*8704; \
    gload16(ks_ + kt8s, ktd_ + tid*16); \
    gload16(ms_ + km0s, kmd_ + tid*8); \
    if (tid < 256) gload16(ms_ + km1vt, kmd_ + (512+tid)*8); \
    else           gload16(vs_ + km1vt, vtd_ + (tid-256)*8); \
    gload16(vs_ + vt1s, vtd_ + (tid+256)*8); \
    if (tid < 320) gload16(vs_ + vt2s, vtd_ + (tid+768)*8); \
} while (0)

    ISSUE(0, 0);
    int cur = 0;
    #pragma unroll 1
    for (int t = 0; t < NT; ++t) {
        if (t < NT-1) ISSUE(t+1, cur^1);    // overwrite-safe: end-barrier of t-1 passed
        if (t < NT-1) {
            if (w < 5) asm volatile("s_waitcnt vmcnt(5)" ::: "memory");
            else       asm volatile("s_waitcnt vmcnt(4)" ::: "memory");
        } else {
            asm volatile("s_waitcnt vmcnt(0)" ::: "memory");
        }
        __builtin_amdgcn_sched_barrier(0);
        __builtin_amdgcn_s_barrier();       // tile t (kt,kmx,vt) visible to all
        __builtin_amdgcn_sched_barrier(0);

        const char* ktb = (const char*)smem + cur*8192;
        const char* kmb = (const char*)smem + 16384 + cur*12288;
        const char* vtb = (const char*)smem + 40960 + cur*17408;
        f32x4 sacc0 = zero, sacc1 = zero;
        i32x4 si0 = zi, si1 = zi;
        __builtin_amdgcn_s_setprio(1);
        #pragma unroll
        for (int s = 0; s < 4; ++s) {        // ip+s dims i8, swapped: mfma(K, Q), K=64
            i32x4 a0 = *(const i32x4*)(ktb + kti[s]);
            i32x4 a1 = *(const i32x4*)(ktb + 4096 + kti[s]);
            si0 = MFMAI8(a0, qip[s], si0);
            si1 = MFMAI8(a1, qip[s], si1);
        }
        #pragma unroll
        for (int ct = 0; ct < 2; ++ct) {     // dist split-precision bf16, dup-block scheme
            const char* kk = kmb + ct*6144;
            bf16x8 ka0 = *(const bf16x8*)(kk + mA);
            bf16x8 ka1 = *(const bf16x8*)(kk + mB);
            bf16x8 ka2 = *(const bf16x8*)(kk + mA + 128);
            bf16x8 kb0 = *(const bf16x8*)(kk + mB + 128);
            bf16x8 kb1 = *(const bf16x8*)(kk + mA + 256);
            bf16x8 kb2 = *(const bf16x8*)(kk + mB + 256);
            f32x4 a = (ct == 0) ? sacc0 : sacc1;
            a = MFMA16(ka0, qdx[0], a);
            a = MFMA16(ka1, qdx[1], a);
            a = MFMA16(ka2, qdx[2], a);
            a = MFMA16(kb0, qdx[3], a);
            a = MFMA16(kb1, qdx[4], a);
            a = MFMA16(kb2, qdx[5], a);
            a = MFMA16(ka0, qdx[3], a);
            a = MFMA16(ka1, qdx[6], a);
            a = MFMA16(kb0, qdx[0], a);
            a = MFMA16(kb1, qdx[7], a);
            if (ct == 0) sacc0 = a; else sacc1 = a;
        }
        __builtin_amdgcn_s_setprio(0);
        // merge i8 ip scores into f32 dist scores
        f32x4 sn0, sn1;
        sn0[0] = sacc0[0] + F * (float)si0[0];
        sn0[1] = sacc0[1] + F * (float)si0[1];
        sn0[2] = sacc0[2] + F * (float)si0[2];
        sn0[3] = sacc0[3] + F * (float)si0[3];
        sn1[0] = sacc1[0] + F * (float)si1[0];
        sn1[1] = sacc1[1] + F * (float)si1[1];
        sn1[2] = sacc1[2] + F * (float)si1[2];
        sn1[3] = sacc1[3] + F * (float)si1[3];

        // online softmax, per-lane q=l15; defer-max THR=8 (log2 units)
        float pm = fmaxf(fmaxf(fmaxf(sn0[0], sn0[1]), fmaxf(sn0[2], sn0[3])),
                         fmaxf(fmaxf(sn1[0], sn1[1]), fmaxf(sn1[2], sn1[3])));
        pm = fmaxf(pm, __shfl_xor(pm, 16, 64));
        pm = fmaxf(pm, __shfl_xor(pm, 32, 64));
        if (!__all(pm <= mreg + 8.0f)) {
            float mnew = fmaxf(mreg, pm);
            float al = fexp2(mreg - mnew);      // 0 on first tile
            mreg = mnew;
            lreg *= al;
            float a0 = __shfl(al, l4*4+0, 64);
            float a1 = __shfl(al, l4*4+1, 64);
            float a2 = __shfl(al, l4*4+2, 64);
            float a3 = __shfl(al, l4*4+3, 64);
            #pragma unroll
            for (int ct = 0; ct < 17; ++ct) {
                oacc[ct][0] *= a0; oacc[ct][1] *= a1;
                oacc[ct][2] *= a2; oacc[ct][3] *= a3;
            }
        }
        float p0 = fexp2(sn0[0] - mreg), p1 = fexp2(sn0[1] - mreg);
        float p2 = fexp2(sn0[2] - mreg), p3 = fexp2(sn0[3] - mreg);
        float p4 = fexp2(sn1[0] - mreg), p5 = fexp2(sn1[1] - mreg);
        float p6 = fexp2(sn1[2] - mreg), p7 = fexp2(sn1[3] - mreg);
        lreg += ((p0 + p1) + (p2 + p3)) + ((p4 + p5) + (p6 + p7));
        unsigned r01, r23, r45, r67;
        asm("v_cvt_pk_bf16_f32 %0, %1, %2" : "=v"(r01) : "v"(p0), "v"(p1));
        asm("v_cvt_pk_bf16_f32 %0, %1, %2" : "=v"(r23) : "v"(p2), "v"(p3));
        asm("v_cvt_pk_bf16_f32 %0, %1, %2" : "=v"(r45) : "v"(p4), "v"(p5));
        asm("v_cvt_pk_bf16_f32 %0, %1, %2" : "=v"(r67) : "v"(p6), "v"(p7));
        {
            char* pbp = (char*)smem;
            *(unsigned*)(pbp + pSeg0 + 0) = r01;
            *(unsigned*)(pbp + pSeg0 + 4) = r23;
            *(unsigned*)(pbp + pSeg1 + 0) = r45;
            *(unsigned*)(pbp + pSeg1 + 4) = r67;
        }

        // PV: P is wave-private (compiler orders ds_write->ds_read); vt visible since barrier
        {
            bf16x8 pa = *(const bf16x8*)((const char*)smem + pRd);
            __builtin_amdgcn_s_setprio(1);
            #pragma unroll
            for (int ct = 0; ct < 17; ++ct) {
                bf16x8 bv = *(const bf16x8*)(vtb + vlane + ct*1024);
                oacc[ct] = MFMA16(pa, bv, oacc[ct]);
            }
            __builtin_amdgcn_s_setprio(0);
        }
        __builtin_amdgcn_s_barrier();        // all waves done reading tile t
        __builtin_amdgcn_sched_barrier(0);
        cur ^= 1;
    }
#undef ISSUE

    // epilogue: finish deferred l, scatter
    float lf = lreg;
    lf += __shfl_xor(lf, 16, 64);
    lf += __shfl_xor(lf, 32, 64);
    const size_t mv_total = (size_t)HH * NN * 256;
    #pragma unroll
    for (int j = 0; j < 4; ++j) {
        float inv = 1.0f / __shfl(lf, l4*4 + j, 64);
        int q = q0 + w*16 + l4*4 + j;
        float* po = out + ((size_t)h*NN + q) * 256 + l15;
        #pragma unroll
        for (int ct = 0; ct < 16; ++ct)
            po[ct*16] = oacc[ct][j] * inv;
        out[mv_total + ((size_t)h*NN + q)*16 + l15] = oacc[16][j] * inv;
    }
}

extern "C" void kernel_launch(void* const* d_in, const int* in_sizes, int n_in,
                              void* d_out, int out_size, void* d_ws, size_t ws_size,
                              hipStream_t stream)
{
    const float* q_mv = (const float*)d_in[0];
    const float* k_mv = (const float*)d_in[1];
    const float* v_mv = (const float*)d_in[2];
    const float* q_s  = (const float*)d_in[3];
    const float* k_s  = (const float*)d_in[4];
    const float* v_s  = (const float*)d_in[5];
    const float* basis_q = (const float*)d_in[6];
    const float* basis_k = (const float*)d_in[7];
    float* out = (float*)d_out;

    signed char* qip8 = (signed char*)d_ws;                         // [8][4096][256] i8
    signed char* kip8 = qip8 + (size_t)HH*NN*DIP;                   // [8][4096][256] i8
    unsigned short* qdx = (unsigned short*)(kip8 + (size_t)HH*NN*DIP); // [8][4096][256] bf16
    unsigned short* kmx = qdx + (size_t)HH*NN*DDX;                  // [8][4096][192] bf16
    unsigned short* vt  = kmx + (size_t)HH*NN*DKM;                  // [8][272][4096] bf16
    // total ws use: ~64.1 MB

    // 1/sqrt(304) * log2(e): dist features carry it; ip carries it via F in-kernel
    const float qscale = 0.08274443827037988f;

    feat_kernel<<<dim3(1024), dim3(256), 0, stream>>>(q_mv, q_s, basis_q, qscale, 1, qip8, qdx);
    feat_kernel<<<dim3(1024), dim3(256), 0, stream>>>(k_mv, k_s, basis_k, 1.0f,   0, kip8, kmx);
    vtrans_kernel<<<dim3(512), dim3(256), 0, stream>>>(v_mv, v_s, vt);
    attn_kernel<<<dim3(256), dim3(512), 0, stream>>>(qip8, qdx, kip8, kmx, vt, out);
}

// Round 13
// 258.460 us; speedup vs baseline: 2.2297x; 1.0855x over previous
//
#include <hip/hip_runtime.h>
#include <math.h>

typedef short bf16x8 __attribute__((ext_vector_type(8)));
typedef float f32x4 __attribute__((ext_vector_type(4)));
typedef int   i32x4 __attribute__((ext_vector_type(4)));

#define HH 8
#define NN 4096
#define DIP 256   // ip(240) + s(16) as int8, no pad
#define DDX 256   // qdx bf16: [hi|hi | mid|lo | mid32-47+16z | hi32-47+16z]
#define DKM 192   // kmx bf16: [mid | lo | hi | hi]
#define DV 272
#define BN 64
#define NT (NN/BN)

typedef const __attribute__((address_space(1))) unsigned int* gp_t;
typedef __attribute__((address_space(3))) unsigned int* lp_t;
__device__ __forceinline__ void gload16(const void* g, void* l) {
    __builtin_amdgcn_global_load_lds((gp_t)g, (lp_t)l, 16, 0, 0);
}

__device__ __forceinline__ unsigned short f2bf(float f) {
    unsigned int u = __float_as_uint(f);
    u = (u + 0x7fffu + ((u >> 16) & 1u)) >> 16;   // RNE
    return (unsigned short)u;
}
__device__ __forceinline__ float bf2f(unsigned short h) {
    return __uint_as_float(((unsigned int)h) << 16);
}
__device__ __forceinline__ float fexp2(float x) {   // 2^x, single v_exp_f32
    float r;
    asm("v_exp_f32 %0, %1" : "=v"(r) : "v"(x));
    return r;
}
__device__ __forceinline__ signed char q8(float x) {  // i8 quant, scale 127/6 (±6 sigma)
    int v = __float2int_rn(x * 21.1666667f);
    v = v < -127 ? -127 : (v > 127 ? 127 : v);
    return (signed char)v;
}

#define MFMA16(A,B,C) __builtin_amdgcn_mfma_f32_16x16x32_bf16((A),(B),(C),0,0,0)
#define MFMAI8(A,B,C) __builtin_amdgcn_mfma_i32_16x16x64_i8((A),(B),(C),0,0,0)

// ---- stage 1a: features. fip[256] = ip+s as i8. fdx bf16: Q-mode 256 / K-mode 192 ----
__global__ void feat_kernel(const float* __restrict__ mv,
                            const float* __restrict__ sv,
                            const float* __restrict__ basis,
                            float scale, int qmode,
                            signed char* __restrict__ fip,
                            unsigned short* __restrict__ fdx)
{
    __shared__ float sb[150];
    int t = threadIdx.x;
    if (t < 150) sb[t] = basis[t];
    __syncthreads();
    int row = blockIdx.x * 32 + (t >> 3);   // (h*4096+n)
    int c = t & 7;
    const float* m = mv + (size_t)row * 256 + c * 32;
    float f[32];
    #pragma unroll
    for (int i = 0; i < 8; ++i) {
        float4 v = ((const float4*)m)[i];
        f[i*4+0] = v.x; f[i*4+1] = v.y; f[i*4+2] = v.z; f[i*4+3] = v.w;
    }
    signed char* ip = fip + (size_t)row * DIP;
    unsigned short* dx = fdx + (size_t)row * (qmode ? DDX : DKM);
    #pragma unroll
    for (int j = 0; j < 30; ++j)
        ip[c*30 + j] = q8(f[1+j]);
    if (c < 2) {
        #pragma unroll
        for (int i = 0; i < 8; ++i)
            ip[240 + c*8 + i] = q8(sv[(size_t)row*16 + c*8 + i]);
    }
    float nn = 1.0f / sqrtf(f[5]*f[5] + 0.001f);
    float tn[5];
    #pragma unroll
    for (int x = 0; x < 5; ++x) tn[x] = f[1+x] * nn;
    #pragma unroll
    for (int z = 0; z < 6; ++z) {
        float acc = 0.f;
        #pragma unroll
        for (int x = 0; x < 5; ++x) {
            #pragma unroll
            for (int y = 0; y < 5; ++y)
                acc = fmaf(sb[(x*5+y)*6 + z] * tn[x], tn[y], acc);
        }
        acc *= scale;
        unsigned short hi = f2bf(acc);
        float r1 = acc - bf2f(hi);
        unsigned short mi = f2bf(r1);
        float r2 = r1 - bf2f(mi);
        unsigned short lo = f2bf(r2);
        int cz = c*6 + z;
        if (qmode) {
            dx[cz]      = hi;  dx[48 + cz]  = hi;
            dx[96 + cz] = mi;  dx[144 + cz] = lo;
            if (cz < 16) { dx[208 + cz] = 0; dx[240 + cz] = 0; }
            if (cz >= 32) { dx[160 + cz] = mi; dx[192 + cz] = hi; }
        } else {
            dx[cz]      = mi;  dx[48 + cz]  = lo;
            dx[96 + cz] = hi;  dx[144 + cz] = hi;
        }
    }
}

// ---- stage 1b: V -> transposed bf16 [8][272][4096] ----
__global__ void vtrans_kernel(const float* __restrict__ vmv,
                              const float* __restrict__ vs,
                              unsigned short* __restrict__ dst)
{
    __shared__ unsigned short tile[64][DV];
    int blk = blockIdx.x;
    int h = blk >> 6;
    int n0 = (blk & 63) << 6;
    int t = threadIdx.x;
    #pragma unroll
    for (int it = 0; it < 16; ++it) {
        int v = t + it*256;
        int r = v >> 6;
        int sg = v & 63;
        float4 x = *(const float4*)(vmv + ((size_t)(h*NN + n0 + r))*256 + sg*4);
        tile[r][sg*4+0] = f2bf(x.x);
        tile[r][sg*4+1] = f2bf(x.y);
        tile[r][sg*4+2] = f2bf(x.z);
        tile[r][sg*4+3] = f2bf(x.w);
    }
    #pragma unroll
    for (int it = 0; it < 4; ++it) {
        int v = t + it*256;
        int r = v >> 4;
        int si = v & 15;
        tile[r][256 + si] = f2bf(vs[((size_t)(h*NN + n0 + r))*16 + si]);
    }
    __syncthreads();
    #pragma unroll
    for (int it = 0; it < 17; ++it) {
        int v = t + it*256;
        int dd = v >> 4;
        int sg = v & 15;
        ushort4 o;
        o.x = tile[sg*4+0][dd];
        o.y = tile[sg*4+1][dd];
        o.z = tile[sg*4+2][dd];
        o.w = tile[sg*4+3][dd];
        *(ushort4*)(dst + ((size_t)(h*DV + dd))*NN + n0 + sg*4) = o;
    }
}

// ---- stage 2: flash attention, BN=64, i8 ip-QKT, 3 barriers/step ----
__global__ __launch_bounds__(512, 1)
void attn_kernel(const signed char*    __restrict__ Qip,
                 const unsigned short* __restrict__ Qdx,
                 const signed char*    __restrict__ Kip,
                 const unsigned short* __restrict__ Kmx,
                 const unsigned short* __restrict__ Vt,
                 float* __restrict__ out)
{
    // bytes: kt 2x16384 [0,32768) | kmx 2x24576 [32768,81920) | vt 34816 [81920,116736) | pb 16384 [116736,133120)
    __shared__ __align__(128) unsigned short smem[66560];   // 133,120 B

    int blk = blockIdx.x;
    int sbk = ((blk & 7) << 5) | (blk >> 3);   // grid 256, bijective XCD swizzle; XCD x = head x
    int h = sbk >> 5;
    int q0 = (sbk & 31) * 128;
    int tid = threadIdx.x;
    int w = tid >> 6;
    int lane = tid & 63;
    int l15 = lane & 15;
    int l4 = lane >> 4;
    int l7l = l15 & 3;
    int l7h = (l15 >> 2) & 1;
    int x7 = l15 & 7;

    // Q ip fragments: i8, B-operand (col=q=l15, k=l4*16+e), 4 K=64 steps
    const signed char* qipr = Qip + (size_t)(h*NN + q0 + w*16 + l15) * DIP + l4*16;
    i32x4 qip[4];
    #pragma unroll
    for (int s = 0; s < 4; ++s) qip[s] = *(const i32x4*)(qipr + s*64);
    // Q dist fragments: bf16 (dup-block scheme)
    const unsigned short* qdxr = Qdx + (size_t)(h*NN + q0 + w*16 + l15) * DDX + l4*8;
    bf16x8 qdx[8];
    #pragma unroll
    for (int ks = 0; ks < 8; ++ks) qdx[ks] = *(const bf16x8*)(qdxr + ks*32);

    // LDS read bases (bytes)
    int cl16 = (l4 ^ l7l) * 16;
    int mA  = l15*384 + cl16 + l7h*64;
    int mB  = l15*384 + cl16 + 64 - l7h*64;
    int kti[4];
    #pragma unroll
    for (int s = 0; s < 4; ++s)
        kti[s] = l15*256 + (((s*4 + l4) ^ x7) << 4);
    int vb0 = (l15>>1)*256 + ((((l15&1)*8 + l4) ^ (l15>>1)) << 4);
    int vb1 = (l15>>1)*256 + ((((l15&1)*8 + 4 + l4) ^ (l15>>1)) << 4);
    int pbW = 116736 + w*2048 + l15*128;
    int pw[4];
    #pragma unroll
    for (int kt4 = 0; kt4 < 4; ++kt4)
        pw[kt4] = pbW + (((kt4*2 + (l4>>1)) ^ x7) << 4) + ((l4&1) << 3);
    int pr0 = pbW + ((l4 ^ x7) << 4);
    int pr1 = pbW + (((4+l4) ^ x7) << 4);

    // DMA source offsets, loop-invariant
    int kts0, kts1;                       // Kip bytes
    { int idx = tid;       int r_ = idx>>4, sg_ = idx&15; kts0 = r_*256 + ((sg_ ^ (r_&7))<<4); }
    { int idx = tid+512;   int r_ = idx>>4, sg_ = idx&15; kts1 = r_*256 + ((sg_ ^ (r_&7))<<4); }
    int kms0, kms1, kms2;                 // Kmx ush
#define KMFL(SLOT, DST) { int r_ = (SLOT)/24, fp_ = (SLOT)%24; \
    int g_ = fp_>>3, po_ = fp_&7; \
    int pl_ = ((((po_>>2)&1) ^ ((r_>>2)&1)) << 2) | ((po_&3) ^ (r_&3)); \
    DST = r_*DKM + (g_*8 + pl_)*8; }
    KMFL(tid, kms0) KMFL(tid+512, kms1) KMFL(tid+1024, kms2)
#undef KMFL
    int vts0, vts1, vts2, vts3, vts4;     // Vt ush
#define VTF(SLOT, DST) { int ch_ = (SLOT)>>4, ps_ = (SLOT)&15; int ls_ = ps_ ^ (ch_&7); \
    DST = (ch_*2 + (ls_>>3))*NN + (ls_&7)*8; }
    VTF(tid, vts0) VTF(tid+512, vts1) VTF(tid+1024, vts2) VTF(tid+1536, vts3) VTF(tid+2048, vts4)
#undef VTF

    const signed char*    kiph = Kip + (size_t)h*NN*DIP;
    const unsigned short* kmxh = Kmx + (size_t)h*NN*DKM;
    const unsigned short* vh   = Vt  + (size_t)h*DV*NN;

    f32x4 zero = {0.f, 0.f, 0.f, 0.f};
    i32x4 zi = {0, 0, 0, 0};
    f32x4 oacc[17];
    #pragma unroll
    for (int ct = 0; ct < 17; ++ct) oacc[ct] = zero;
    float mreg = -__builtin_inff();
    float lreg = 0.f;
    const float F = 0.08274443827037988f * (6.0f/127.0f) * (6.0f/127.0f);

    // K staging: 5 VMEM instr/wave (uniform). V staging: waves 0-1: 5, waves 2-7: 4.
#define ISSUE_K(TILE, BUF) do { \
    const signed char* ks_ = kiph + (size_t)(TILE)*BN*DIP; \
    const unsigned short* ms_ = kmxh + (size_t)(TILE)*BN*DKM; \
    char* ktd_ = (char*)smem + (BUF)*16384; \
    char* kmd_ = (char*)smem + 32768 + (BUF)*24576; \
    gload16(ks_ + kts0, ktd_ + tid*16); \
    gload16(ks_ + kts1, ktd_ + (tid+512)*16); \
    gload16(ms_ + kms0, kmd_ + tid*16); \
    gload16(ms_ + kms1, kmd_ + (tid+512)*16); \
    gload16(ms_ + kms2, kmd_ + (tid+1024)*16); \
} while (0)

#define ISSUE_V(TILE) do { \
    const unsigned short* vs_ = vh + (TILE)*BN; \
    char* vtd_ = (char*)smem + 81920; \
    gload16(vs_ + vts0, vtd_ + tid*16); \
    gload16(vs_ + vts1, vtd_ + (tid+512)*16); \
    gload16(vs_ + vts2, vtd_ + (tid+1024)*16); \
    gload16(vs_ + vts3, vtd_ + (tid+1536)*16); \
    if (tid < 128) gload16(vs_ + vts4, vtd_ + (tid+2048)*16); \
} while (0)

    ISSUE_K(0, 0);
    int cur = 0;
    #pragma unroll 1
    for (int t = 0; t < NT; ++t) {
        ISSUE_V(t);                          // vt free: BAR3(t-1) passed
        if (t < NT-1) {
            ISSUE_K(t+1, cur^1);             // kt/kmx(t-1) buffer free since QKT(t-1)
            // drain K(t) (oldest 5); keep V(t) 4|5 + K(t+1) 5 in flight
            if (w < 2) asm volatile("s_waitcnt vmcnt(10)" ::: "memory");
            else       asm volatile("s_waitcnt vmcnt(9)"  ::: "memory");
        } else {
            if (w < 2) asm volatile("s_waitcnt vmcnt(5)" ::: "memory");
            else       asm volatile("s_waitcnt vmcnt(4)" ::: "memory");
        }
        __builtin_amdgcn_sched_barrier(0);
        __builtin_amdgcn_s_barrier();        // BAR1: K tile t visible
        __builtin_amdgcn_sched_barrier(0);

        const char* ktb = (const char*)smem + cur*16384;
        const char* kmb = (const char*)smem + 32768 + cur*24576;

        f32x4 sf[4];
        i32x4 si[4];
        __builtin_amdgcn_s_setprio(1);
        #pragma unroll
        for (int kt4 = 0; kt4 < 4; ++kt4) {
            const char* kb = ktb + kt4*4096;
            i32x4 a = zi;
            a = MFMAI8(*(const i32x4*)(kb + kti[0]), qip[0], a);
            a = MFMAI8(*(const i32x4*)(kb + kti[1]), qip[1], a);
            a = MFMAI8(*(const i32x4*)(kb + kti[2]), qip[2], a);
            a = MFMAI8(*(const i32x4*)(kb + kti[3]), qip[3], a);
            si[kt4] = a;
            const char* kk = kmb + kt4*6144;
            bf16x8 ka0 = *(const bf16x8*)(kk + mA);
            bf16x8 ka1 = *(const bf16x8*)(kk + mB);
            bf16x8 ka2 = *(const bf16x8*)(kk + mA + 128);
            bf16x8 kb0 = *(const bf16x8*)(kk + mB + 128);
            bf16x8 kb1 = *(const bf16x8*)(kk + mA + 256);
            bf16x8 kb2 = *(const bf16x8*)(kk + mB + 256);
            f32x4 d = zero;
            d = MFMA16(ka0, qdx[0], d);
            d = MFMA16(ka1, qdx[1], d);
            d = MFMA16(ka2, qdx[2], d);
            d = MFMA16(kb0, qdx[3], d);
            d = MFMA16(kb1, qdx[4], d);
            d = MFMA16(kb2, qdx[5], d);
            d = MFMA16(ka0, qdx[3], d);
            d = MFMA16(ka1, qdx[6], d);
            d = MFMA16(kb0, qdx[0], d);
            d = MFMA16(kb1, qdx[7], d);
            sf[kt4] = d;
        }
        __builtin_amdgcn_s_setprio(0);

        // merge i8 + dist scores
        f32x4 sn[4];
        #pragma unroll
        for (int kt4 = 0; kt4 < 4; ++kt4) {
            sn[kt4][0] = sf[kt4][0] + F * (float)si[kt4][0];
            sn[kt4][1] = sf[kt4][1] + F * (float)si[kt4][1];
            sn[kt4][2] = sf[kt4][2] + F * (float)si[kt4][2];
            sn[kt4][3] = sf[kt4][3] + F * (float)si[kt4][3];
        }

        // online softmax over 64 keys, per-lane q=l15; defer-max THR=8 (log2 units)
        float pm = fmaxf(
            fmaxf(fmaxf(fmaxf(sn[0][0], sn[0][1]), fmaxf(sn[0][2], sn[0][3])),
                  fmaxf(fmaxf(sn[1][0], sn[1][1]), fmaxf(sn[1][2], sn[1][3]))),
            fmaxf(fmaxf(fmaxf(sn[2][0], sn[2][1]), fmaxf(sn[2][2], sn[2][3])),
                  fmaxf(fmaxf(sn[3][0], sn[3][1]), fmaxf(sn[3][2], sn[3][3]))));
        pm = fmaxf(pm, __shfl_xor(pm, 16, 64));
        pm = fmaxf(pm, __shfl_xor(pm, 32, 64));
        if (!__all(pm <= mreg + 8.0f)) {
            float mnew = fmaxf(mreg, pm);
            float al = fexp2(mreg - mnew);      // 0 on first tile
            mreg = mnew;
            lreg *= al;
            float a0 = __shfl(al, l4*4+0, 64);
            float a1 = __shfl(al, l4*4+1, 64);
            float a2 = __shfl(al, l4*4+2, 64);
            float a3 = __shfl(al, l4*4+3, 64);
            #pragma unroll
            for (int ct = 0; ct < 17; ++ct) {
                oacc[ct][0] *= a0; oacc[ct][1] *= a1;
                oacc[ct][2] *= a2; oacc[ct][3] *= a3;
            }
        }
        char* pbp = (char*)smem;
        #pragma unroll
        for (int kt4 = 0; kt4 < 4; ++kt4) {
            float p0 = fexp2(sn[kt4][0] - mreg), p1 = fexp2(sn[kt4][1] - mreg);
            float p2 = fexp2(sn[kt4][2] - mreg), p3 = fexp2(sn[kt4][3] - mreg);
            lreg += (p0 + p1) + (p2 + p3);
            unsigned r01, r23;
            asm("v_cvt_pk_bf16_f32 %0, %1, %2" : "=v"(r01) : "v"(p0), "v"(p1));
            asm("v_cvt_pk_bf16_f32 %0, %1, %2" : "=v"(r23) : "v"(p2), "v"(p3));
            unsigned long long pk = ((unsigned long long)r23 << 32) | (unsigned long long)r01;
            *(unsigned long long*)(pbp + pw[kt4]) = pk;
        }

        // drain V(t): remaining in flight = K(t+1) (5) or nothing on last iter
        if (t < NT-1) asm volatile("s_waitcnt vmcnt(5)" ::: "memory");
        else          asm volatile("s_waitcnt vmcnt(0)" ::: "memory");
        __builtin_amdgcn_sched_barrier(0);
        __builtin_amdgcn_s_barrier();        // BAR2: V tile + everyone's P ready
        __builtin_amdgcn_sched_barrier(0);

        // PV: O += P(16x64) @ V(64x272)
        {
            bf16x8 pa0 = *(const bf16x8*)(pbp + pr0);
            bf16x8 pa1 = *(const bf16x8*)(pbp + pr1);
            const char* vtb = (const char*)smem + 81920;
            __builtin_amdgcn_s_setprio(1);
            #pragma unroll
            for (int ct = 0; ct < 17; ++ct) {
                bf16x8 bv0 = *(const bf16x8*)(vtb + ct*2048 + vb0);
                oacc[ct] = MFMA16(pa0, bv0, oacc[ct]);
            }
            #pragma unroll
            for (int ct = 0; ct < 17; ++ct) {
                bf16x8 bv1 = *(const bf16x8*)(vtb + ct*2048 + vb1);
                oacc[ct] = MFMA16(pa1, bv1, oacc[ct]);
            }
            __builtin_amdgcn_s_setprio(0);
        }
        __builtin_amdgcn_s_barrier();        // BAR3: all waves done reading vt
        __builtin_amdgcn_sched_barrier(0);
        cur ^= 1;
    }
#undef ISSUE_K
#undef ISSUE_V

    // epilogue: finish deferred l, scatter
    float lf = lreg;
    lf += __shfl_xor(lf, 16, 64);
    lf += __shfl_xor(lf, 32, 64);
    const size_t mv_total = (size_t)HH * NN * 256;
    #pragma unroll
    for (int j = 0; j < 4; ++j) {
        float inv = 1.0f / __shfl(lf, l4*4 + j, 64);
        int q = q0 + w*16 + l4*4 + j;
        float* po = out + ((size_t)h*NN + q) * 256 + l15;
        #pragma unroll
        for (int ct = 0; ct < 16; ++ct)
            po[ct*16] = oacc[ct][j] * inv;
        out[mv_total + ((size_t)h*NN + q)*16 + l15] = oacc[16][j] * inv;
    }
}

extern "C" void kernel_launch(void* const* d_in, const int* in_sizes, int n_in,
                              void* d_out, int out_size, void* d_ws, size_t ws_size,
                              hipStream_t stream)
{
    const float* q_mv = (const float*)d_in[0];
    const float* k_mv = (const float*)d_in[1];
    const float* v_mv = (const float*)d_in[2];
    const float* q_s  = (const float*)d_in[3];
    const float* k_s  = (const float*)d_in[4];
    const float* v_s  = (const float*)d_in[5];
    const float* basis_q = (const float*)d_in[6];
    const float* basis_k = (const float*)d_in[7];
    float* out = (float*)d_out;

    signed char* qip8 = (signed char*)d_ws;                         // [8][4096][256] i8
    signed char* kip8 = qip8 + (size_t)HH*NN*DIP;                   // [8][4096][256] i8
    unsigned short* qdx = (unsigned short*)(kip8 + (size_t)HH*NN*DIP); // [8][4096][256] bf16
    unsigned short* kmx = qdx + (size_t)HH*NN*DDX;                  // [8][4096][192] bf16
    unsigned short* vt  = kmx + (size_t)HH*NN*DKM;                  // [8][272][4096] bf16
    // total ws use: ~64.1 MB

    // 1/sqrt(304) * log2(e): dist features carry it; ip carries it via F in-kernel
    const float qscale = 0.08274443827037988f;

    feat_kernel<<<dim3(1024), dim3(256), 0, stream>>>(q_mv, q_s, basis_q, qscale, 1, qip8, qdx);
    feat_kernel<<<dim3(1024), dim3(256), 0, stream>>>(k_mv, k_s, basis_k, 1.0f,   0, kip8, kmx);
    vtrans_kernel<<<dim3(512), dim3(256), 0, stream>>>(v_mv, v_s, vt);
    attn_kernel<<<dim3(256), dim3(512), 0, stream>>>(qip8, qdx, kip8, kmx, vt, out);
}